// Round 1
// baseline (240.672 us; speedup 1.0000x reference)
//
#include <hip/hip_runtime.h>

// Problem constants (fixed by setup_inputs: (2, 64, 320, 320), stoken 16x16)
#define KB   2
#define KC   64
#define KH   320
#define KW   320
#define KSH  16
#define KSW  16
#define KNSH 20
#define KNSW 20
#define KNS  400           // KNSH*KNSW
#define KN   102400        // KH*KW

// ---------------------------------------------------------------------------
// Kernel A: spix0 = per-block mean of pixel features.
// Grid: KB*KC*KNSH workgroups x 320 threads. Each wg handles one (b, c, block-row).
// Thread t covers column t; reduce groups of 16 lanes (one superpixel column).
__global__ __launch_bounds__(320) void block_mean_kernel(
    const float* __restrict__ pf, float* __restrict__ spix) {
  int wg = blockIdx.x;
  int rb = wg % KNSH;
  int c  = (wg / KNSH) % KC;
  int b  = wg / (KNSH * KC);
  int t  = threadIdx.x;  // 0..319

  const float* row0 = pf + ((size_t)(b * KC + c) * KH + rb * KSH) * KW;
  float acc = 0.f;
#pragma unroll
  for (int i = 0; i < KSH; ++i) acc += row0[i * KW + t];

  // reduce within groups of 16 lanes
#pragma unroll
  for (int off = 8; off > 0; off >>= 1) acc += __shfl_down(acc, off, 16);

  if ((t & 15) == 0)
    spix[(b * KC + c) * KNS + rb * KNSW + (t >> 4)] = acc * (1.0f / (KSH * KSW));
}

// ---------------------------------------------------------------------------
// Kernel B: per-pixel 9-candidate distances + masked softmax -> aff (B, 9, N).
// Grid: KB*KNS workgroups x 256 threads (one thread per pixel of the block).
__global__ __launch_bounds__(256) void dist_aff_kernel(
    const float* __restrict__ pf, const float* __restrict__ spix,
    float* __restrict__ aff) {
  __shared__ float scand[9][KC];

  int wg = blockIdx.x;
  int s  = wg % KNS;
  int b  = wg / KNS;
  int sr = s / KNSW, sc = s % KNSW;
  int t  = threadIdx.x;

  // stage the 9 candidate centroids (zeros for invalid; masked later)
  for (int idx = t; idx < 9 * KC; idx += 256) {
    int k = idx >> 6, c = idx & 63;
    int rr = sr + k / 3 - 1, cc = sc + k % 3 - 1;
    float v = 0.f;
    if (rr >= 0 && rr < KNSH && cc >= 0 && cc < KNSW)
      v = spix[(b * KC + c) * KNS + rr * KNSW + cc];
    scand[k][c] = v;
  }
  __syncthreads();

  int i = t >> 4, j = t & 15;
  int p = (sr * KSH + i) * KW + sc * KSW + j;
  const float* pfb = pf + (size_t)b * KC * KN + p;

  float d[9];
#pragma unroll
  for (int k = 0; k < 9; ++k) d[k] = 0.f;

  for (int c = 0; c < KC; ++c) {
    float x = pfb[(size_t)c * KN];
#pragma unroll
    for (int k = 0; k < 9; ++k) {
      float df = x - scand[k][c];
      d[k] = fmaf(df, df, d[k]);
    }
  }

  // masked softmax over -d (min-d trick); own candidate (k=4) always valid
  float m = 3.4e38f;
#pragma unroll
  for (int k = 0; k < 9; ++k) {
    int rr = sr + k / 3 - 1, cc = sc + k % 3 - 1;
    bool valid = (rr >= 0 && rr < KNSH && cc >= 0 && cc < KNSW);
    if (valid) m = fminf(m, d[k]);
  }
  float e[9];
  float sum = 0.f;
#pragma unroll
  for (int k = 0; k < 9; ++k) {
    int rr = sr + k / 3 - 1, cc = sc + k % 3 - 1;
    bool valid = (rr >= 0 && rr < KNSH && cc >= 0 && cc < KNSW);
    e[k] = valid ? __expf(m - d[k]) : 0.f;
    sum += e[k];
  }
  float inv = 1.0f / sum;
#pragma unroll
  for (int k = 0; k < 9; ++k)
    aff[((size_t)b * 9 + k) * KN + p] = e[k] * inv;
}

// ---------------------------------------------------------------------------
// Kernel C: spix1[b,c,s] = sum_p aff * pf / (sum_p aff + 1e-16), gather form.
// Grid: KB*KNS workgroups x 64 threads (lane = channel).
__global__ __launch_bounds__(64) void update_spix_kernel(
    const float* __restrict__ pf, const float* __restrict__ aff,
    float* __restrict__ spix1) {
  int wg   = blockIdx.x;
  int s    = wg % KNS;
  int b    = wg / KNS;
  int sr   = s / KNSW, sc = s % KNSW;
  int lane = threadIdx.x;  // channel

  const float* pfc = pf + (size_t)(b * KC + lane) * KN;
  float num = 0.f, den = 0.f;

#pragma unroll
  for (int k = 0; k < 9; ++k) {
    int rr = sr + k / 3 - 1, cc = sc + k % 3 - 1;
    if (rr < 0 || rr >= KNSH || cc < 0 || cc >= KNSW) continue;
    // pixels in block (rr,cc): their candidate pointing at s is index 8-k
    const float* affk = aff + ((size_t)b * 9 + (8 - k)) * KN;
    int pbase = (rr * KSH) * KW + cc * KSW;
    for (int i = 0; i < KSH; ++i) {
      int prow = pbase + i * KW;
#pragma unroll
      for (int j = 0; j < KSW; ++j) {
        int p = prow + j;
        float a = affk[p];   // wave-uniform -> scalarized
        float x = pfc[p];
        num = fmaf(a, x, num);
        den += a;
      }
    }
  }
  spix1[(b * KC + lane) * KNS + s] = num / (den + 1e-16f);
}

// ---------------------------------------------------------------------------
// Kernel D: write the full dense output (B, ns, N): zero everywhere except
// the 3x3-neighborhood pixels, which copy from aff. float4 stores, 1 row of
// the output per (b,s) workgroup-column; grid.y splits the row 4 ways.
__global__ __launch_bounds__(256) void write_out_kernel(
    const float* __restrict__ aff, float* __restrict__ out) {
  int wg = blockIdx.x;
  int s  = wg % KNS;
  int b  = wg / KNS;
  int sr = s / KNSW, sc = s % KNSW;
  int t  = threadIdx.x;

  float4* orow = (float4*)(out + ((size_t)b * KNS + s) * KN);
  const float* affb = aff + (size_t)b * 9 * KN;

  // 25600 float4 per row; 4 slabs x 25 iters x 256 threads
  int it0 = blockIdx.y * 25;
#pragma unroll 5
  for (int ii = 0; ii < 25; ++ii) {
    int q = (it0 + ii) * 256 + t;  // float4 index in row
    int p = q * 4;
    unsigned r   = (unsigned)p / KW;
    unsigned col = (unsigned)p - r * KW;
    int r0 = (int)(r >> 4), c0 = (int)(col >> 4);
    int dr = sr - r0, dc = sc - c0;
    float4 v = make_float4(0.f, 0.f, 0.f, 0.f);
    if (dr >= -1 && dr <= 1 && dc >= -1 && dc <= 1) {
      int k = (dr + 1) * 3 + (dc + 1);
      v = *(const float4*)(affb + (size_t)k * KN + p);
    }
    orow[q] = v;
  }
}

// ---------------------------------------------------------------------------
extern "C" void kernel_launch(void* const* d_in, const int* in_sizes, int n_in,
                              void* d_out, int out_size, void* d_ws, size_t ws_size,
                              hipStream_t stream) {
  const float* pf = (const float*)d_in[0];
  float* out = (float*)d_out;

  // workspace layout (floats): spix0 [51200] | spix1 [51200] | aff [1843200]
  float* spix0 = (float*)d_ws;
  float* spix1 = spix0 + (size_t)KB * KC * KNS;
  float* affws = spix1 + (size_t)KB * KC * KNS;

  // 1) initial centroids
  block_mean_kernel<<<KB * KC * KNSH, 320, 0, stream>>>(pf, spix0);
  // 2) iter 0 affinities
  dist_aff_kernel<<<KB * KNS, 256, 0, stream>>>(pf, spix0, affws);
  // 3) centroid update
  update_spix_kernel<<<KB * KNS, 64, 0, stream>>>(pf, affws, spix1);
  // 4) iter 1 affinities (overwrite aff buffer)
  dist_aff_kernel<<<KB * KNS, 256, 0, stream>>>(pf, spix1, affws);
  // 5) dense output write
  dim3 gridD(KB * KNS, 4);
  write_out_kernel<<<gridD, 256, 0, stream>>>(affws, out);
}

// Round 3
// 185.520 us; speedup vs baseline: 1.2973x; 1.2973x over previous
//
#include <hip/hip_runtime.h>

// Problem constants (fixed by setup_inputs: (2, 64, 320, 320), stoken 16x16)
#define KB   2
#define KC   64
#define KH   320
#define KW   320
#define KSH  16
#define KSW  16
#define KNSH 20
#define KNSW 20
#define KNS  400           // KNSH*KNSW
#define KN   102400        // KH*KW

typedef float float4v __attribute__((ext_vector_type(4)));

// ---------------------------------------------------------------------------
// Kernel A: spix0 = per-block mean of pixel features.
__global__ __launch_bounds__(320) void block_mean_kernel(
    const float* __restrict__ pf, float* __restrict__ spix) {
  int wg = blockIdx.x;
  int rb = wg % KNSH;
  int c  = (wg / KNSH) % KC;
  int b  = wg / (KNSH * KC);
  int t  = threadIdx.x;  // 0..319

  const float* row0 = pf + ((size_t)(b * KC + c) * KH + rb * KSH) * KW;
  float acc = 0.f;
#pragma unroll
  for (int i = 0; i < KSH; ++i) acc += row0[i * KW + t];

#pragma unroll
  for (int off = 8; off > 0; off >>= 1) acc += __shfl_down(acc, off, 16);

  if ((t & 15) == 0)
    spix[(b * KC + c) * KNS + rb * KNSW + (t >> 4)] = acc * (1.0f / (KSH * KSW));
}

// ---------------------------------------------------------------------------
// Kernel B: per-pixel 9-candidate distances + masked softmax -> aff (B, 9, N).
__global__ __launch_bounds__(256) void dist_aff_kernel(
    const float* __restrict__ pf, const float* __restrict__ spix,
    float* __restrict__ aff) {
  __shared__ float scand[9][KC];

  int wg = blockIdx.x;
  int s  = wg % KNS;
  int b  = wg / KNS;
  int sr = s / KNSW, sc = s % KNSW;
  int t  = threadIdx.x;

  for (int idx = t; idx < 9 * KC; idx += 256) {
    int k = idx >> 6, c = idx & 63;
    int rr = sr + k / 3 - 1, cc = sc + k % 3 - 1;
    float v = 0.f;
    if (rr >= 0 && rr < KNSH && cc >= 0 && cc < KNSW)
      v = spix[(b * KC + c) * KNS + rr * KNSW + cc];
    scand[k][c] = v;
  }
  __syncthreads();

  int i = t >> 4, j = t & 15;
  int p = (sr * KSH + i) * KW + sc * KSW + j;
  const float* pfb = pf + (size_t)b * KC * KN + p;

  float d[9];
#pragma unroll
  for (int k = 0; k < 9; ++k) d[k] = 0.f;

  for (int c = 0; c < KC; ++c) {
    float x = pfb[(size_t)c * KN];
#pragma unroll
    for (int k = 0; k < 9; ++k) {
      float df = x - scand[k][c];
      d[k] = fmaf(df, df, d[k]);
    }
  }

  float m = 3.4e38f;
#pragma unroll
  for (int k = 0; k < 9; ++k) {
    int rr = sr + k / 3 - 1, cc = sc + k % 3 - 1;
    bool valid = (rr >= 0 && rr < KNSH && cc >= 0 && cc < KNSW);
    if (valid) m = fminf(m, d[k]);
  }
  float e[9];
  float sum = 0.f;
#pragma unroll
  for (int k = 0; k < 9; ++k) {
    int rr = sr + k / 3 - 1, cc = sc + k % 3 - 1;
    bool valid = (rr >= 0 && rr < KNSH && cc >= 0 && cc < KNSW);
    e[k] = valid ? __expf(m - d[k]) : 0.f;
    sum += e[k];
  }
  float inv = 1.0f / sum;
#pragma unroll
  for (int k = 0; k < 9; ++k)
    aff[((size_t)b * 9 + k) * KN + p] = e[k] * inv;
}

// ---------------------------------------------------------------------------
// Kernel C v2: spix1[b,c,s] = (sum_p aff*pf) / (sum_p aff + 1e-16), gather.
// One wg per (b,s), 256 threads = 4 waves. Stage the 9-block affinities in
// LDS; wave w owns channels 16w..16w+15; lanes sweep pixels with float4
// coalesced loads (1 instr per 256-pixel block), shuffle-reduce per channel.
__global__ __launch_bounds__(256) void update_spix_kernel(
    const float* __restrict__ pf, const float* __restrict__ aff,
    float* __restrict__ spix1) {
  __shared__ __align__(16) float aff_s[9][256];
  __shared__ float red_s[4];
  __shared__ float invden_s;

  int wg = blockIdx.x;
  int s  = wg % KNS;
  int b  = wg / KNS;
  int sr = s / KNSW, sc = s % KNSW;
  int t  = threadIdx.x;

  // stage aff (invalid neighbors -> 0) and accumulate denominator
  int ti = t >> 4, tj = t & 15;
  float psum = 0.f;
#pragma unroll
  for (int k = 0; k < 9; ++k) {
    int rr = sr + k / 3 - 1, cc = sc + k % 3 - 1;
    float a = 0.f;
    if (rr >= 0 && rr < KNSH && cc >= 0 && cc < KNSW) {
      int p = (rr * KSH + ti) * KW + cc * KSW + tj;
      a = aff[((size_t)b * 9 + (8 - k)) * KN + p];
    }
    aff_s[k][t] = a;
    psum += a;
  }
#pragma unroll
  for (int off = 32; off > 0; off >>= 1) psum += __shfl_down(psum, off, 64);
  if ((t & 63) == 0) red_s[t >> 6] = psum;
  __syncthreads();
  if (t == 0) invden_s = 1.0f / (red_s[0] + red_s[1] + red_s[2] + red_s[3] + 1e-16f);
  __syncthreads();
  float inv_den = invden_s;

  // clamped block bases (aff_s==0 masks invalid contributions)
  int pbase[9];
#pragma unroll
  for (int k = 0; k < 9; ++k) {
    int rr = min(max(sr + k / 3 - 1, 0), KNSH - 1);
    int cc = min(max(sc + k % 3 - 1, 0), KNSW - 1);
    pbase[k] = (rr * KSH) * KW + cc * KSW;
  }

  int w = t >> 6, l = t & 63;
  int li = l >> 2, lj4 = (l & 3) * 4;
  const float* pfb = pf + (size_t)b * KC * KN;

#pragma unroll
  for (int ci = 0; ci < 16; ++ci) {
    int c = w * 16 + ci;
    const float* pfc = pfb + (size_t)c * KN;
    float acc = 0.f;
#pragma unroll
    for (int k = 0; k < 9; ++k) {
      const float4v x = *(const float4v*)(pfc + pbase[k] + li * KW + lj4);
      const float4v a = *(const float4v*)(&aff_s[k][l * 4]);
      acc = fmaf(x.x, a.x, acc);
      acc = fmaf(x.y, a.y, acc);
      acc = fmaf(x.z, a.z, acc);
      acc = fmaf(x.w, a.w, acc);
    }
#pragma unroll
    for (int off = 32; off > 0; off >>= 1) acc += __shfl_down(acc, off, 64);
    if (l == 0) spix1[((size_t)b * KC + c) * KNS + s] = acc * inv_den;
  }
}

// ---------------------------------------------------------------------------
// Kernel D: write the full dense output (B, ns, N).
__global__ __launch_bounds__(256) void write_out_kernel(
    const float* __restrict__ aff, float* __restrict__ out) {
  int wg = blockIdx.x;
  int s  = wg % KNS;
  int b  = wg / KNS;
  int sr = s / KNSW, sc = s % KNSW;
  int t  = threadIdx.x;

  float4v* orow = (float4v*)(out + ((size_t)b * KNS + s) * KN);
  const float* affb = aff + (size_t)b * 9 * KN;

  int it0 = blockIdx.y * 25;
#pragma unroll 5
  for (int ii = 0; ii < 25; ++ii) {
    int q = (it0 + ii) * 256 + t;  // float4 index in row
    int p = q * 4;
    unsigned r   = (unsigned)p / KW;
    unsigned col = (unsigned)p - r * KW;
    int r0 = (int)(r >> 4), c0 = (int)(col >> 4);
    int dr = sr - r0, dc = sc - c0;
    float4v v = (float4v)(0.f);
    if (dr >= -1 && dr <= 1 && dc >= -1 && dc <= 1) {
      int k = (dr + 1) * 3 + (dc + 1);
      v = *(const float4v*)(affb + (size_t)k * KN + p);
    }
    __builtin_nontemporal_store(v, &orow[q]);
  }
}

// ---------------------------------------------------------------------------
extern "C" void kernel_launch(void* const* d_in, const int* in_sizes, int n_in,
                              void* d_out, int out_size, void* d_ws, size_t ws_size,
                              hipStream_t stream) {
  const float* pf = (const float*)d_in[0];
  float* out = (float*)d_out;

  float* spix0 = (float*)d_ws;
  float* spix1 = spix0 + (size_t)KB * KC * KNS;
  float* affws = spix1 + (size_t)KB * KC * KNS;

  block_mean_kernel<<<KB * KC * KNSH, 320, 0, stream>>>(pf, spix0);
  dist_aff_kernel<<<KB * KNS, 256, 0, stream>>>(pf, spix0, affws);
  update_spix_kernel<<<KB * KNS, 256, 0, stream>>>(pf, affws, spix1);
  dist_aff_kernel<<<KB * KNS, 256, 0, stream>>>(pf, spix1, affws);
  dim3 gridD(KB * KNS, 4);
  write_out_kernel<<<gridD, 256, 0, stream>>>(affws, out);
}